// Round 3
// baseline (181.458 us; speedup 1.0000x reference)
//
#include <hip/hip_runtime.h>

// LocalizationLoss: B=1048576, N=3, C=7. output (B,3,7) fp32, target (B,3,5) fp32.
// result = (5*(Sx+Sy+2*Swh) + 3*Sce - 0.5*Sbce)/(B*N) + 0.5   (scalar fp32)
//
// R1: per-block partials instead of one global atomic (77->59us).
// R2: barrier-free. Each WAVE stages its own 64 rows into a wave-private LDS
// region and reads them back — same-wave LDS ordering via lgkmcnt only, no
// __syncthreads. Waves are fully independent -> latency hiding limited only
// by occupancy (16 waves/CU), not by block-wide barrier drain.

#define NBLK 4096            // B/256 chunks of 256 rows; 4 waves x 64 rows each
#define INV_BN (1.0f / 3145728.0f)

__global__ __launch_bounds__(256) void loc_loss_kernel(
    const float* __restrict__ gout, const float* __restrict__ gtgt,
    float* __restrict__ ws) {
  __shared__ float s_out[4][64 * 21];  // per-wave regions, 5376 B each
  __shared__ float s_tgt[4][64 * 15];  // 3840 B each

  const int tid = threadIdx.x;
  const int w = tid >> 6;
  const int lane = tid & 63;
  const size_t row0 = (size_t)blockIdx.x * 256 + (size_t)w * 64;

  // Wave-chunk bases: row0 multiple of 64 -> row0*84B and row0*60B are 16B-aligned.
  const float4* go4 = (const float4*)(gout + row0 * 21);  // 336 float4
  const float4* gt4 = (const float4*)(gtgt + row0 * 15);  // 240 float4

  // Issue ALL global loads first (up to 9 in flight per lane), then LDS writes.
  float4 vo[6], vt[4];
  #pragma unroll
  for (int i = 0; i < 5; ++i) vo[i] = go4[lane + 64 * i];
  if (lane < 16) vo[5] = go4[lane + 320];
  #pragma unroll
  for (int i = 0; i < 3; ++i) vt[i] = gt4[lane + 64 * i];
  if (lane < 48) vt[3] = gt4[lane + 192];

  float4* so4 = (float4*)s_out[w];
  float4* st4 = (float4*)s_tgt[w];
  #pragma unroll
  for (int i = 0; i < 5; ++i) so4[lane + 64 * i] = vo[i];
  if (lane < 16) so4[lane + 320] = vo[5];
  #pragma unroll
  for (int i = 0; i < 3; ++i) st4[lane + 64 * i] = vt[i];
  if (lane < 48) st4[lane + 192] = vt[3];

  // Same-wave readback; LDS strides 21/15 odd -> conflict-free on 32 banks.
  const float* o = s_out[w] + lane * 21;
  const float* t = s_tgt[w] + lane * 15;

  float sbce = 0.f, sce = 0.f, sx = 0.f, sy = 0.f, swh = 0.f;
  float L[3][3];
  int cls[3];
  #pragma unroll
  for (int n = 0; n < 3; ++n) {
    const float p  = o[n * 7 + 0];
    const float tt = t[n * 5 + 0];
    sbce += tt * __logf(p) + (1.f - tt) * __logf(1.f - p);
    const bool mk = (tt != 0.f);
    const float m = mk ? 1.f : 0.f;
    const float dx = o[n * 7 + 1] * m - t[n * 5 + 1];
    sx += dx * dx;
    const float dy = o[n * 7 + 2] * m - t[n * 5 + 2];
    sy += dy * dy;
    const float sp = mk ? __builtin_sqrtf(o[n * 7 + 3]) : 0.f;
    const float dw = sp - __builtin_sqrtf(t[n * 5 + 3]);
    swh += dw * dw;
    L[n][0] = o[n * 7 + 4] * m;
    L[n][1] = o[n * 7 + 5] * m;
    L[n][2] = o[n * 7 + 6] * m;
    cls[n] = (int)t[n * 5 + 4];
  }
  // log-softmax over anchor axis per class channel j; nll[j] = lse_j - L[cls[j]][j]
  #pragma unroll
  for (int j = 0; j < 3; ++j) {
    // masked logits are in [0,1] -> exp is safe without max-subtraction
    const float e = __expf(L[0][j]) + __expf(L[1][j]) + __expf(L[2][j]);
    const float lse = __logf(e);
    const int idx = cls[j];
    const float sel = (idx == 0) ? L[0][j] : ((idx == 1) ? L[1][j] : L[2][j]);
    sce += lse - sel;
  }

  float acc = 5.f * (sx + sy + 2.f * swh) + 3.f * sce - 0.5f * sbce;

  // per-wave shuffle reduce -> one partial per wave, no barrier
  #pragma unroll
  for (int off = 32; off > 0; off >>= 1) acc += __shfl_down(acc, off, 64);
  if (lane == 0) ws[(size_t)blockIdx.x * 4 + w] = acc;
}

__global__ __launch_bounds__(256) void loc_loss_finalize(
    const float* __restrict__ ws, float* __restrict__ out) {
  __shared__ float s_wave[4];
  const int tid = threadIdx.x;
  const float4* w4 = (const float4*)ws;  // 16384 partials = 4096 float4
  float acc = 0.f;
  #pragma unroll
  for (int i = 0; i < 16; ++i) {
    float4 v = w4[tid + 256 * i];
    acc += (v.x + v.y) + (v.z + v.w);
  }
  #pragma unroll
  for (int off = 32; off > 0; off >>= 1) acc += __shfl_down(acc, off, 64);
  if ((tid & 63) == 0) s_wave[tid >> 6] = acc;
  __syncthreads();
  if (tid == 0) {
    out[0] = (s_wave[0] + s_wave[1] + s_wave[2] + s_wave[3]) * INV_BN + 0.5f;
  }
}

extern "C" void kernel_launch(void* const* d_in, const int* in_sizes, int n_in,
                              void* d_out, int out_size, void* d_ws, size_t ws_size,
                              hipStream_t stream) {
  const float* gout = (const float*)d_in[0];  // (B,3,7)
  const float* gtgt = (const float*)d_in[1];  // (B,3,5)
  float* ws = (float*)d_ws;                   // 16384 floats = 64 KB
  float* out = (float*)d_out;

  loc_loss_kernel<<<NBLK, 256, 0, stream>>>(gout, gtgt, ws);
  loc_loss_finalize<<<1, 256, 0, stream>>>(ws, out);
}

// Round 4
// 176.980 us; speedup vs baseline: 1.0253x; 1.0253x over previous
//
#include <hip/hip_runtime.h>

// LocalizationLoss: B=1048576, N=3, C=7. output (B,3,7) fp32, target (B,3,5) fp32.
// result = (5*(Sx+Sy+2*Swh) + 3*Sce - 0.5*Sbce)/(B*N) + 0.5   (scalar fp32)
//
// R1: per-block partials instead of one global atomic (77->59us).
// R2: barrier-free wave-private staging — neutral (62us), and the register
//     staging buffers spilled to scratch (WRITE_SIZE 128KB -> 16.4MB).
// R3: global_load_lds(16B) staging (no VGPR round-trip, no spills) + each wave
//     processes 4 chunks of 64 rows with double-buffered wave-private LDS and
//     software pipelining (prefetch k+1 during compute k). No barriers at all;
//     A/B are distinct __shared__ arrays so the memory legalizer can emit
//     fine-grained per-buffer vmcnt waits instead of vmcnt(0).

#define NBLK 1024            // 1024 blocks x 4 waves x 4 chunks x 64 rows = B
#define CHUNKS 4
#define INV_BN (1.0f / 3145728.0f)

__device__ __forceinline__ void gl16(const float4* g, float4* l) {
  __builtin_amdgcn_global_load_lds(
      (const __attribute__((address_space(1))) unsigned int*)g,
      (__attribute__((address_space(3))) unsigned int*)l, 16, 0, 0);
}

// Stage 64 rows (64*21 + 64*15 floats) into wave-private LDS, direct-to-LDS.
// LDS base args are wave-uniform; HW lands lane L at base + 16*L.
__device__ __forceinline__ void stage_chunk(const float* __restrict__ gout,
                                            const float* __restrict__ gtgt,
                                            size_t row0, int lane,
                                            float* so, float* st) {
  const float4* go4 = (const float4*)(gout + row0 * 21);  // 336 float4
  const float4* gt4 = (const float4*)(gtgt + row0 * 15);  // 240 float4
  float4* so4 = (float4*)so;
  float4* st4 = (float4*)st;
  #pragma unroll
  for (int i = 0; i < 5; ++i) gl16(go4 + lane + 64 * i, so4 + 64 * i);
  if (lane < 16) gl16(go4 + lane + 320, so4 + 320);
  #pragma unroll
  for (int i = 0; i < 3; ++i) gl16(gt4 + lane + 64 * i, st4 + 64 * i);
  if (lane < 48) gl16(gt4 + lane + 192, st4 + 192);
}

// Per-lane row math from LDS. Strides 21/15 odd -> conflict-free on 32 banks.
__device__ __forceinline__ float compute_chunk(const float* so, const float* st,
                                               int lane) {
  const float* o = so + lane * 21;
  const float* t = st + lane * 15;
  float sbce = 0.f, sce = 0.f, sx = 0.f, sy = 0.f, swh = 0.f;
  float L[3][3];
  int cls[3];
  #pragma unroll
  for (int n = 0; n < 3; ++n) {
    const float p  = o[n * 7 + 0];
    const float tt = t[n * 5 + 0];
    sbce += tt * __logf(p) + (1.f - tt) * __logf(1.f - p);
    const bool mk = (tt != 0.f);
    const float m = mk ? 1.f : 0.f;
    const float dx = o[n * 7 + 1] * m - t[n * 5 + 1];
    sx += dx * dx;
    const float dy = o[n * 7 + 2] * m - t[n * 5 + 2];
    sy += dy * dy;
    const float sp = mk ? __builtin_sqrtf(o[n * 7 + 3]) : 0.f;
    const float dw = sp - __builtin_sqrtf(t[n * 5 + 3]);
    swh += dw * dw;
    L[n][0] = o[n * 7 + 4] * m;
    L[n][1] = o[n * 7 + 5] * m;
    L[n][2] = o[n * 7 + 6] * m;
    cls[n] = (int)t[n * 5 + 4];
  }
  #pragma unroll
  for (int j = 0; j < 3; ++j) {
    // masked logits in [0,1] -> exp safe without max-subtraction
    const float e = __expf(L[0][j]) + __expf(L[1][j]) + __expf(L[2][j]);
    const float lse = __logf(e);
    const int idx = cls[j];
    const float sel = (idx == 0) ? L[0][j] : ((idx == 1) ? L[1][j] : L[2][j]);
    sce += lse - sel;
  }
  return 5.f * (sx + sy + 2.f * swh) + 3.f * sce - 0.5f * sbce;
}

__global__ __launch_bounds__(256) void loc_loss_kernel(
    const float* __restrict__ gout, const float* __restrict__ gtgt,
    float* __restrict__ ws) {
  // Two wave-private staging buffers per wave: 64*(21+15)*4B = 9216 B each.
  __shared__ float sA_out[4][64 * 21];
  __shared__ float sA_tgt[4][64 * 15];
  __shared__ float sB_out[4][64 * 21];
  __shared__ float sB_tgt[4][64 * 15];

  const int tid = threadIdx.x;
  const int w = tid >> 6;
  const int lane = tid & 63;
  // Wave's 4 chunks are contiguous: base row for this wave.
  const size_t wrow0 = ((size_t)blockIdx.x * 4 + w) * (64 * CHUNKS);

  float acc = 0.f;
  // Software pipeline: prefetch c+1 into the other buffer while computing c.
  stage_chunk(gout, gtgt, wrow0, lane, sA_out[w], sA_tgt[w]);
  #pragma unroll
  for (int c = 0; c < CHUNKS; c += 2) {
    if (c + 1 < CHUNKS)
      stage_chunk(gout, gtgt, wrow0 + (size_t)(c + 1) * 64, lane,
                  sB_out[w], sB_tgt[w]);
    acc += compute_chunk(sA_out[w], sA_tgt[w], lane);
    if (c + 2 < CHUNKS)
      stage_chunk(gout, gtgt, wrow0 + (size_t)(c + 2) * 64, lane,
                  sA_out[w], sA_tgt[w]);
    if (c + 1 < CHUNKS)
      acc += compute_chunk(sB_out[w], sB_tgt[w], lane);
  }

  // per-wave shuffle reduce -> one partial per wave (4096 total)
  #pragma unroll
  for (int off = 32; off > 0; off >>= 1) acc += __shfl_down(acc, off, 64);
  if (lane == 0) ws[(size_t)blockIdx.x * 4 + w] = acc;
}

__global__ __launch_bounds__(256) void loc_loss_finalize(
    const float* __restrict__ ws, float* __restrict__ out) {
  __shared__ float s_wave[4];
  const int tid = threadIdx.x;
  const float4* w4 = (const float4*)ws;  // 4096 partials = 1024 float4
  float acc = 0.f;
  #pragma unroll
  for (int i = 0; i < 4; ++i) {
    float4 v = w4[tid + 256 * i];
    acc += (v.x + v.y) + (v.z + v.w);
  }
  #pragma unroll
  for (int off = 32; off > 0; off >>= 1) acc += __shfl_down(acc, off, 64);
  if ((tid & 63) == 0) s_wave[tid >> 6] = acc;
  __syncthreads();
  if (tid == 0) {
    out[0] = (s_wave[0] + s_wave[1] + s_wave[2] + s_wave[3]) * INV_BN + 0.5f;
  }
}

extern "C" void kernel_launch(void* const* d_in, const int* in_sizes, int n_in,
                              void* d_out, int out_size, void* d_ws, size_t ws_size,
                              hipStream_t stream) {
  const float* gout = (const float*)d_in[0];  // (B,3,7)
  const float* gtgt = (const float*)d_in[1];  // (B,3,5)
  float* ws = (float*)d_ws;                   // 4096 floats = 16 KB
  float* out = (float*)d_out;

  loc_loss_kernel<<<NBLK, 256, 0, stream>>>(gout, gtgt, ws);
  loc_loss_finalize<<<1, 256, 0, stream>>>(ws, out);
}